// Round 3
// baseline (647.445 us; speedup 1.0000x reference)
//
#include <hip/hip_runtime.h>

typedef unsigned short u16;
typedef __bf16 bf16_t;
typedef bf16_t bf16x8 __attribute__((ext_vector_type(8)));
typedef float f32x4 __attribute__((ext_vector_type(4)));

#define T_TOK 8192
#define DIM   1024
#define FF    512
#define NE    16
#define RBASE_SHARED (2 * T_TOK)     // shared group rowbase = 16384
#define NROWS (RBASE_SHARED + T_TOK) // 24576 total row-slots
#define MAXTILES 256

__device__ __forceinline__ u16 f2bf(float f) {
  union { float f; unsigned u; } v; v.f = f;
  unsigned r = v.u + 0x7FFFu + ((v.u >> 16) & 1u);
  return (u16)(r >> 16);
}
__device__ __forceinline__ float bf2f(u16 h) {
  union { unsigned u; float f; } v; v.u = ((unsigned)h) << 16; return v.f;
}

// async global->LDS, 16B per lane; LDS dest = wave-uniform base + lane*16
#define GLL16(g, l) __builtin_amdgcn_global_load_lds( \
    (const __attribute__((address_space(1))) void*)(g), \
    (__attribute__((address_space(3))) void*)(l), 16, 0, 0)

// ---------------- fused fp32 -> bf16 convert for all 7 inputs ----------------
#define X4   2097152   // x: 8192*1024/4
#define SW4  131072    // each shared weight: 512*1024/4
#define EW4  2097152   // each expert weight: 16*512*1024/4
#define TOT4 (X4 + 3 * SW4 + 3 * EW4)

__global__ __launch_bounds__(256) void cvt_all_kernel(
    const float* __restrict__ x, const float* __restrict__ sw1,
    const float* __restrict__ sw2, const float* __restrict__ sw3,
    const float* __restrict__ ew1, const float* __restrict__ ew2,
    const float* __restrict__ ew3,
    u16* __restrict__ xb, u16* __restrict__ sw1b, u16* __restrict__ sw2b,
    u16* __restrict__ sw3b, u16* __restrict__ ew1b, u16* __restrict__ ew2b,
    u16* __restrict__ ew3b) {
  int i = blockIdx.x * 256 + threadIdx.x;
  const float* s; u16* dst; int j;
  if (i < X4)                       { s = x;   dst = xb;   j = i; }
  else if (i < X4 + SW4)            { s = sw1; dst = sw1b; j = i - X4; }
  else if (i < X4 + 2 * SW4)        { s = sw2; dst = sw2b; j = i - (X4 + SW4); }
  else if (i < X4 + 3 * SW4)        { s = sw3; dst = sw3b; j = i - (X4 + 2 * SW4); }
  else if (i < X4 + 3 * SW4 + EW4)      { s = ew1; dst = ew1b; j = i - (X4 + 3 * SW4); }
  else if (i < X4 + 3 * SW4 + 2 * EW4)  { s = ew2; dst = ew2b; j = i - (X4 + 3 * SW4 + EW4); }
  else if (i < TOT4)                    { s = ew3; dst = ew3b; j = i - (X4 + 3 * SW4 + 2 * EW4); }
  else return;
  float4 v = reinterpret_cast<const float4*>(s)[j];
  ushort4 o;
  o.x = f2bf(v.x); o.y = f2bf(v.y); o.z = f2bf(v.z); o.w = f2bf(v.w);
  reinterpret_cast<ushort4*>(dst)[j] = o;
}

// ---------------- router: fp32, coalesced; one wave per 2 tokens ----------------
__global__ __launch_bounds__(256) void router_kernel(
    const float* __restrict__ x, const float* __restrict__ gw,
    const float* __restrict__ ebias, float* __restrict__ probs,
    int* __restrict__ topi, float* __restrict__ topw, int* __restrict__ cnt) {
  int wave = (blockIdx.x * 256 + threadIdx.x) >> 6;
  int lane = threadIdx.x & 63;
  int t0 = wave * 2;
  const float4* x0 = reinterpret_cast<const float4*>(x + (size_t)t0 * DIM);
  const float4* x1 = reinterpret_cast<const float4*>(x + (size_t)(t0 + 1) * DIM);
  const float4* gv = reinterpret_cast<const float4*>(gw);
  float4 xa[4], xc[4];
#pragma unroll
  for (int j = 0; j < 4; ++j) { xa[j] = x0[j * 64 + lane]; xc[j] = x1[j * 64 + lane]; }
  float p0[16], p1[16];
#pragma unroll
  for (int e = 0; e < NE; ++e) {
    float s0 = 0.f, s1 = 0.f;
#pragma unroll
    for (int j = 0; j < 4; ++j) {
      float4 g = gv[e * 256 + j * 64 + lane];
      s0 += xa[j].x * g.x + xa[j].y * g.y + xa[j].z * g.z + xa[j].w * g.w;
      s1 += xc[j].x * g.x + xc[j].y * g.y + xc[j].z * g.z + xc[j].w * g.w;
    }
#pragma unroll
    for (int d = 1; d < 64; d <<= 1) { s0 += __shfl_xor(s0, d); s1 += __shfl_xor(s1, d); }
    float b = ebias[e];
    p0[e] = s0 + b; p1[e] = s1 + b;
  }
  // softmax (redundant on all lanes, registers only)
  float m0 = p0[0], m1 = p1[0];
#pragma unroll
  for (int e = 1; e < NE; ++e) { m0 = fmaxf(m0, p0[e]); m1 = fmaxf(m1, p1[e]); }
  float sum0 = 0.f, sum1 = 0.f;
#pragma unroll
  for (int e = 0; e < NE; ++e) {
    p0[e] = __expf(p0[e] - m0); sum0 += p0[e];
    p1[e] = __expf(p1[e] - m1); sum1 += p1[e];
  }
  float inv0 = 1.f / sum0, inv1 = 1.f / sum1;
#pragma unroll
  for (int e = 0; e < NE; ++e) { p0[e] *= inv0; p1[e] *= inv1; }
  if (lane == 0) {
#pragma unroll
    for (int j = 0; j < 4; ++j) {
      reinterpret_cast<float4*>(probs + (size_t)t0 * NE)[j] =
          make_float4(p0[4 * j], p0[4 * j + 1], p0[4 * j + 2], p0[4 * j + 3]);
      reinterpret_cast<float4*>(probs + (size_t)(t0 + 1) * NE)[j] =
          make_float4(p1[4 * j], p1[4 * j + 1], p1[4 * j + 2], p1[4 * j + 3]);
    }
    // top-2, lowest-index tie-break (matches lax.top_k)
    float b1 = -1.f, b2 = -1.f; int i1 = 0, i2 = 0;
#pragma unroll
    for (int e = 0; e < NE; ++e) {
      float pe = p0[e];
      if (pe > b1) { b2 = b1; i2 = i1; b1 = pe; i1 = e; }
      else if (pe > b2) { b2 = pe; i2 = e; }
    }
    float ws = b1 + b2;
    topi[t0 * 2] = i1; topi[t0 * 2 + 1] = i2;
    topw[t0 * 2] = b1 / ws; topw[t0 * 2 + 1] = b2 / ws;
    atomicAdd(&cnt[i1], 1); atomicAdd(&cnt[i2], 1);
    b1 = -1.f; b2 = -1.f; i1 = 0; i2 = 0;
#pragma unroll
    for (int e = 0; e < NE; ++e) {
      float pe = p1[e];
      if (pe > b1) { b2 = b1; i2 = i1; b1 = pe; i1 = e; }
      else if (pe > b2) { b2 = pe; i2 = e; }
    }
    ws = b1 + b2;
    int t1 = t0 + 1;
    topi[t1 * 2] = i1; topi[t1 * 2 + 1] = i2;
    topw[t1 * 2] = b1 / ws; topw[t1 * 2 + 1] = b2 / ws;
    atomicAdd(&cnt[i1], 1); atomicAdd(&cnt[i2], 1);
  }
}

// ---------------- scan: prefix offsets + dense tile table ----------------
__global__ void scan_kernel(const int* __restrict__ cnt, int* __restrict__ offs,
                            int* __restrict__ cursor, int2* __restrict__ tab) {
  if (threadIdx.x == 0) {
    int a = 0;
    for (int e = 0; e < NE; ++e) { offs[e] = a; a += cnt[e]; }
    offs[NE] = RBASE_SHARED;
    int n = 0;
    for (int e = 0; e <= NE; ++e) {
      int M = (e == NE) ? T_TOK : cnt[e];
      for (int m0 = 0; m0 < M; m0 += 128) { tab[n].x = e; tab[n].y = m0; ++n; }
    }
    for (; n < MAXTILES; ++n) { tab[n].x = -1; tab[n].y = 0; }
  }
  if (threadIdx.x < NE) cursor[threadIdx.x] = 0;
}

// ---------------- scatter tokens to slots (+identity shared slots) ----------------
__global__ __launch_bounds__(256) void scatter_kernel(
    const int* __restrict__ topi, const float* __restrict__ topw,
    const int* __restrict__ offs, int* __restrict__ cursor,
    int* __restrict__ idx, float* __restrict__ cwl, int* __restrict__ slotmap) {
  int t = blockIdx.x * 256 + threadIdx.x;
  if (t >= T_TOK) return;
  for (int s = 0; s < 2; ++s) {
    int e = topi[t * 2 + s];
    int p = atomicAdd(&cursor[e], 1);
    int slot = offs[e] + p;
    idx[slot] = t;
    cwl[slot] = topw[t * 2 + s];
    slotmap[t * 3 + s] = slot;
  }
  int sh = RBASE_SHARED + t;
  idx[sh] = t;
  cwl[sh] = 1.0f;
  slotmap[t * 3 + 2] = sh;
}

// ---------------- grouped GEMM1: G = silu(A@W1^T) * (A@W3^T), bf16 ----------------
__global__ __launch_bounds__(256) void gemm_silu_kernel(
    const u16* __restrict__ A, const u16* __restrict__ sw1b, const u16* __restrict__ sw3b,
    const u16* __restrict__ ew1b, const u16* __restrict__ ew3b, u16* __restrict__ G,
    const int2* __restrict__ tab, const int* __restrict__ offs,
    const int* __restrict__ cnt, const int* __restrict__ gidx) {
  const int K = DIM;
  int2 te = tab[blockIdx.x];
  int e = te.x;
  if (e < 0) return;
  int m0 = te.y;
  int M = (e == NE) ? T_TOK : cnt[e];
  int rowbase = offs[e];
  const u16* B1 = (e == NE) ? sw1b : ew1b + (size_t)e * FF * K;
  const u16* B3 = (e == NE) ? sw3b : ew3b + (size_t)e * FF * K;
  int n0 = blockIdx.y * 128;

  __shared__ u16 As[128 * 32], B1s[128 * 32], B3s[128 * 32];

  int tid = threadIdx.x;
  int lane = tid & 63, wv = tid >> 6;
  int srow = tid >> 2, sg = tid & 3;
  int sk0 = (sg ^ ((srow >> 1) & 3)) * 8;
  int sk1 = (sg ^ (((srow + 64) >> 1) & 3)) * 8;
  int r0 = min(m0 + srow, M - 1);
  int r1 = min(m0 + srow + 64, M - 1);
  int ga0 = gidx[rowbase + r0];
  int ga1 = gidx[rowbase + r1];
  const u16* Ap0 = A + (size_t)ga0 * K + sk0;
  const u16* Ap1 = A + (size_t)ga1 * K + sk1;
  const u16* B1p0 = B1 + (size_t)(n0 + srow) * K + sk0;
  const u16* B1p1 = B1 + (size_t)(n0 + srow + 64) * K + sk1;
  const u16* B3p0 = B3 + (size_t)(n0 + srow) * K + sk0;
  const u16* B3p1 = B3 + (size_t)(n0 + srow + 64) * K + sk1;
  u16* lA0 = As + wv * 512;   u16* lA1 = As + 2048 + wv * 512;
  u16* lB10 = B1s + wv * 512; u16* lB11 = B1s + 2048 + wv * 512;
  u16* lB30 = B3s + wv * 512; u16* lB31 = B3s + 2048 + wv * 512;

  int ln15 = lane & 15, qd = lane >> 4;
  int qsw = (qd ^ ((ln15 >> 1) & 3)) * 8;
  int wm = (wv >> 1) * 64, wn = (wv & 1) * 64;
  int aoff = (wm + ln15) * 32 + qsw;
  int boff = (wn + ln15) * 32 + qsw;

  f32x4 acc1[4][4] = {};
  f32x4 acc3[4][4] = {};

  for (int kt = 0; kt < K; kt += 32) {
    GLL16(Ap0 + kt, lA0);   GLL16(Ap1 + kt, lA1);
    GLL16(B1p0 + kt, lB10); GLL16(B1p1 + kt, lB11);
    GLL16(B3p0 + kt, lB30); GLL16(B3p1 + kt, lB31);
    __syncthreads();
    bf16x8 af[4], b1f[4], b3f[4];
#pragma unroll
    for (int i = 0; i < 4; ++i) {
      af[i]  = *reinterpret_cast<const bf16x8*>(&As[aoff + i * 512]);
      b1f[i] = *reinterpret_cast<const bf16x8*>(&B1s[boff + i * 512]);
      b3f[i] = *reinterpret_cast<const bf16x8*>(&B3s[boff + i * 512]);
    }
#pragma unroll
    for (int i = 0; i < 4; ++i)
#pragma unroll
      for (int j = 0; j < 4; ++j) {
        acc1[i][j] = __builtin_amdgcn_mfma_f32_16x16x32_bf16(af[i], b1f[j], acc1[i][j], 0, 0, 0);
        acc3[i][j] = __builtin_amdgcn_mfma_f32_16x16x32_bf16(af[i], b3f[j], acc3[i][j], 0, 0, 0);
      }
    __syncthreads();
  }

  int mrem = M - m0;
#pragma unroll
  for (int i = 0; i < 4; ++i)
#pragma unroll
    for (int r = 0; r < 4; ++r) {
      int ml = wm + i * 16 + qd * 4 + r;
      if (ml < mrem) {
        size_t orow = (size_t)(rowbase + m0 + ml);
#pragma unroll
        for (int j = 0; j < 4; ++j) {
          float z1 = acc1[i][j][r], z3 = acc3[i][j][r];
          float g = z1 / (1.f + __expf(-z1)) * z3;
          G[orow * FF + n0 + wn + j * 16 + ln15] = f2bf(g);
        }
      }
    }
}

// ---------------- grouped GEMM2: O[slot] = cw * (G @ W2^T), bf16 ----------------
__global__ __launch_bounds__(256) void gemm_out_kernel(
    const u16* __restrict__ Gb, const u16* __restrict__ sw2b, const u16* __restrict__ ew2b,
    u16* __restrict__ O, const int2* __restrict__ tab, const int* __restrict__ offs,
    const int* __restrict__ cnt, const float* __restrict__ cwl) {
  const int K = FF;
  int2 te = tab[blockIdx.x];
  int e = te.x;
  if (e < 0) return;
  int m0 = te.y;
  int M = (e == NE) ? T_TOK : cnt[e];
  int rowbase = offs[e];
  const u16* B = (e == NE) ? sw2b : ew2b + (size_t)e * DIM * K;
  int n0 = blockIdx.y * 128;

  __shared__ u16 As[128 * 32], Bs[128 * 32];

  int tid = threadIdx.x;
  int lane = tid & 63, wv = tid >> 6;
  int srow = tid >> 2, sg = tid & 3;
  int sk0 = (sg ^ ((srow >> 1) & 3)) * 8;
  int sk1 = (sg ^ (((srow + 64) >> 1) & 3)) * 8;
  int r0 = min(m0 + srow, M - 1);
  int r1 = min(m0 + srow + 64, M - 1);
  const u16* Ap0 = Gb + (size_t)(rowbase + r0) * K + sk0;
  const u16* Ap1 = Gb + (size_t)(rowbase + r1) * K + sk1;
  const u16* Bp0 = B + (size_t)(n0 + srow) * K + sk0;
  const u16* Bp1 = B + (size_t)(n0 + srow + 64) * K + sk1;
  u16* lA0 = As + wv * 512; u16* lA1 = As + 2048 + wv * 512;
  u16* lB0 = Bs + wv * 512; u16* lB1 = Bs + 2048 + wv * 512;

  int ln15 = lane & 15, qd = lane >> 4;
  int qsw = (qd ^ ((ln15 >> 1) & 3)) * 8;
  int wm = (wv >> 1) * 64, wn = (wv & 1) * 64;
  int aoff = (wm + ln15) * 32 + qsw;
  int boff = (wn + ln15) * 32 + qsw;

  f32x4 acc[4][4] = {};

  for (int kt = 0; kt < K; kt += 32) {
    GLL16(Ap0 + kt, lA0); GLL16(Ap1 + kt, lA1);
    GLL16(Bp0 + kt, lB0); GLL16(Bp1 + kt, lB1);
    __syncthreads();
    bf16x8 af[4], bf[4];
#pragma unroll
    for (int i = 0; i < 4; ++i) {
      af[i] = *reinterpret_cast<const bf16x8*>(&As[aoff + i * 512]);
      bf[i] = *reinterpret_cast<const bf16x8*>(&Bs[boff + i * 512]);
    }
#pragma unroll
    for (int i = 0; i < 4; ++i)
#pragma unroll
      for (int j = 0; j < 4; ++j)
        acc[i][j] = __builtin_amdgcn_mfma_f32_16x16x32_bf16(af[i], bf[j], acc[i][j], 0, 0, 0);
    __syncthreads();
  }

  int mrem = M - m0;
#pragma unroll
  for (int i = 0; i < 4; ++i)
#pragma unroll
    for (int r = 0; r < 4; ++r) {
      int ml = wm + i * 16 + qd * 4 + r;
      if (ml < mrem) {
        int slot = rowbase + m0 + ml;
        float cw = cwl[slot];
#pragma unroll
        for (int j = 0; j < 4; ++j)
          O[(size_t)slot * DIM + n0 + wn + j * 16 + ln15] = f2bf(acc[i][j][r] * cw);
      }
    }
}

// ---------------- combine: y[t] = sum of token's 3 slot rows ----------------
__global__ __launch_bounds__(256) void combine_kernel(
    const u16* __restrict__ O, const int* __restrict__ slotmap, float* __restrict__ y) {
  int t = blockIdx.x;
  int c = threadIdx.x;
  int s0 = slotmap[t * 3], s1 = slotmap[t * 3 + 1], s2 = slotmap[t * 3 + 2];
  ushort4 a = reinterpret_cast<const ushort4*>(O + (size_t)s0 * DIM)[c];
  ushort4 b = reinterpret_cast<const ushort4*>(O + (size_t)s1 * DIM)[c];
  ushort4 d = reinterpret_cast<const ushort4*>(O + (size_t)s2 * DIM)[c];
  float4 r;
  r.x = bf2f(a.x) + bf2f(b.x) + bf2f(d.x);
  r.y = bf2f(a.y) + bf2f(b.y) + bf2f(d.y);
  r.z = bf2f(a.z) + bf2f(b.z) + bf2f(d.z);
  r.w = bf2f(a.w) + bf2f(b.w) + bf2f(d.w);
  reinterpret_cast<float4*>(y + (size_t)t * DIM)[c] = r;
}

// ---------------- launcher ----------------
extern "C" void kernel_launch(void* const* d_in, const int* in_sizes, int n_in,
                              void* d_out, int out_size, void* d_ws, size_t ws_size,
                              hipStream_t stream) {
  const float* x     = (const float*)d_in[0];
  const float* gw    = (const float*)d_in[1];
  const float* ebias = (const float*)d_in[2];
  const float* sw1   = (const float*)d_in[3];
  const float* sw2   = (const float*)d_in[4];
  const float* sw3   = (const float*)d_in[5];
  const float* ew1   = (const float*)d_in[6];
  const float* ew2   = (const float*)d_in[7];
  const float* ew3   = (const float*)d_in[8];
  float* y = (float*)d_out;
  float* probs = y + (size_t)T_TOK * DIM;

  char* ws = (char*)d_ws;
  size_t o = 0;
  auto alloc = [&](size_t bytes) -> char* {
    char* p = ws + o;
    o = (o + bytes + 255) & ~(size_t)255;
    return p;
  };
  u16* G    = (u16*)alloc((size_t)NROWS * FF * 2);
  u16* sw1b = (u16*)alloc((size_t)FF * DIM * 2);
  u16* sw2b = (u16*)alloc((size_t)FF * DIM * 2);
  u16* sw3b = (u16*)alloc((size_t)FF * DIM * 2);
  u16* ew2b = (u16*)alloc((size_t)NE * FF * DIM * 2);
  // aliased region: [xb | ew1b | ew3b] (live through silu) == O (live after silu)
  char* aliasBase = alloc((size_t)NROWS * DIM * 2);
  u16* xb   = (u16*)aliasBase;
  u16* ew1b = (u16*)(aliasBase + (size_t)T_TOK * DIM * 2);
  u16* ew3b = (u16*)(aliasBase + (size_t)T_TOK * DIM * 2 + (size_t)NE * FF * DIM * 2);
  u16* O    = (u16*)aliasBase;
  int*   topi    = (int*)alloc(T_TOK * 2 * 4);
  float* topw    = (float*)alloc(T_TOK * 2 * 4);
  int*   idx     = (int*)alloc(NROWS * 4);
  float* cwl     = (float*)alloc(NROWS * 4);
  int*   slotmap = (int*)alloc(T_TOK * 3 * 4);
  int2*  tab     = (int2*)alloc(MAXTILES * 8);
  int*   cnt     = (int*)alloc(256);
  int*   offs    = (int*)alloc(256);
  int*   cursor  = (int*)alloc(256);

  hipMemsetAsync(cnt, 0, NE * 4, stream);

  router_kernel<<<T_TOK / 8, 256, 0, stream>>>(x, gw, ebias, probs, topi, topw, cnt);
  cvt_all_kernel<<<TOT4 / 256, 256, 0, stream>>>(x, sw1, sw2, sw3, ew1, ew2, ew3,
                                                 xb, sw1b, sw2b, sw3b, ew1b, ew2b, ew3b);
  scan_kernel<<<1, 64, 0, stream>>>(cnt, offs, cursor, tab);
  scatter_kernel<<<T_TOK / 256, 256, 0, stream>>>(topi, topw, offs, cursor, idx, cwl, slotmap);

  gemm_silu_kernel<<<dim3(MAXTILES, 4, 1), 256, 0, stream>>>(
      xb, sw1b, sw3b, ew1b, ew3b, G, tab, offs, cnt, idx);
  gemm_out_kernel<<<dim3(MAXTILES, 8, 1), 256, 0, stream>>>(
      G, sw2b, ew2b, O, tab, offs, cnt, cwl);
  combine_kernel<<<T_TOK, 256, 0, stream>>>(O, slotmap, y);
}

// Round 6
// 458.230 us; speedup vs baseline: 1.4129x; 1.4129x over previous
//
#include <hip/hip_runtime.h>

typedef unsigned short u16;
typedef __bf16 bf16_t;
typedef bf16_t bf16x8 __attribute__((ext_vector_type(8)));
typedef float f32x4 __attribute__((ext_vector_type(4)));

#define T_TOK 8192
#define DIM   1024
#define FF    512
#define NE    16
#define RBASE_SHARED (2 * T_TOK)     // shared group rowbase = 16384
#define NROWS (RBASE_SHARED + T_TOK) // 24576 total row-slots
#define MAXTILES 256
#define NSEG 512                     // 16 tokens per segment

__device__ __forceinline__ u16 f2bf(float f) {
  union { float f; unsigned u; } v; v.f = f;
  unsigned r = v.u + 0x7FFFu + ((v.u >> 16) & 1u);
  return (u16)(r >> 16);
}
__device__ __forceinline__ float bf2f(u16 h) {
  union { unsigned u; float f; } v; v.u = ((unsigned)h) << 16; return v.f;
}
__device__ __forceinline__ int clampi(int v, int lo, int hi) {
  return v < lo ? lo : (v > hi ? hi : v);
}

// async global->LDS, 16B per lane; LDS dest = wave-uniform base + lane*16
#define GLL16(g, l) __builtin_amdgcn_global_load_lds( \
    (const __attribute__((address_space(1))) void*)(g), \
    (__attribute__((address_space(3))) void*)(l), 16, 0, 0)

// ---------------- fused fp32 -> bf16 convert for all 7 inputs ----------------
#define X4   2097152   // x: 8192*1024/4
#define SW4  131072    // each shared weight: 512*1024/4
#define EW4  2097152   // each expert weight set: 16*512*1024/4
#define TOT4 (X4 + 3 * SW4 + 3 * EW4)

__global__ __launch_bounds__(256) void cvt_all_kernel(
    const float* __restrict__ x, const float* __restrict__ sw1,
    const float* __restrict__ sw2, const float* __restrict__ sw3,
    const float* __restrict__ ew1, const float* __restrict__ ew2,
    const float* __restrict__ ew3,
    u16* __restrict__ xb, u16* __restrict__ sw1b, u16* __restrict__ sw2b,
    u16* __restrict__ sw3b, u16* __restrict__ ew1b, u16* __restrict__ ew2b,
    u16* __restrict__ ew3b) {
  int i = blockIdx.x * 256 + threadIdx.x;
  const float* s; u16* dst; int j;
  if (i < X4)                       { s = x;   dst = xb;   j = i; }
  else if (i < X4 + SW4)            { s = sw1; dst = sw1b; j = i - X4; }
  else if (i < X4 + 2 * SW4)        { s = sw2; dst = sw2b; j = i - (X4 + SW4); }
  else if (i < X4 + 3 * SW4)        { s = sw3; dst = sw3b; j = i - (X4 + 2 * SW4); }
  else if (i < X4 + 3 * SW4 + EW4)      { s = ew1; dst = ew1b; j = i - (X4 + 3 * SW4); }
  else if (i < X4 + 3 * SW4 + 2 * EW4)  { s = ew2; dst = ew2b; j = i - (X4 + 3 * SW4 + EW4); }
  else if (i < TOT4)                    { s = ew3; dst = ew3b; j = i - (X4 + 3 * SW4 + 2 * EW4); }
  else return;
  float4 v = reinterpret_cast<const float4*>(s)[j];
  ushort4 o;
  o.x = f2bf(v.x); o.y = f2bf(v.y); o.z = f2bf(v.z); o.w = f2bf(v.w);
  reinterpret_cast<ushort4*>(dst)[j] = o;
}

// ---------------- router: fp32, coalesced, NO global atomics ----------------
// 512 blocks x 256 thr; block = 16-token segment; wave handles 2 pairs.
__global__ __launch_bounds__(256) void router_kernel(
    const float* __restrict__ x, const float* __restrict__ gw,
    const float* __restrict__ ebias, float* __restrict__ probs,
    int* __restrict__ topi, float* __restrict__ topw, int* __restrict__ cnt_seg) {
  __shared__ int hist[16];
  int tid = threadIdx.x;
  int lane = tid & 63, w = tid >> 6;
  if (tid < 16) hist[tid] = 0;
  __syncthreads();
  const float4* gv = reinterpret_cast<const float4*>(gw);
  for (int it = 0; it < 2; ++it) {
    int t0 = blockIdx.x * 16 + (w + 4 * it) * 2;
    const float4* x0 = reinterpret_cast<const float4*>(x + (size_t)t0 * DIM);
    const float4* x1 = reinterpret_cast<const float4*>(x + (size_t)(t0 + 1) * DIM);
    float4 xa[4], xc[4];
#pragma unroll
    for (int j = 0; j < 4; ++j) { xa[j] = x0[j * 64 + lane]; xc[j] = x1[j * 64 + lane]; }
    float p0[16], p1[16];
#pragma unroll
    for (int e = 0; e < NE; ++e) {
      float s0 = 0.f, s1 = 0.f;
#pragma unroll
      for (int j = 0; j < 4; ++j) {
        float4 g = gv[e * 256 + j * 64 + lane];
        s0 += xa[j].x * g.x + xa[j].y * g.y + xa[j].z * g.z + xa[j].w * g.w;
        s1 += xc[j].x * g.x + xc[j].y * g.y + xc[j].z * g.z + xc[j].w * g.w;
      }
#pragma unroll
      for (int d = 1; d < 64; d <<= 1) { s0 += __shfl_xor(s0, d); s1 += __shfl_xor(s1, d); }
      float b = ebias[e];
      p0[e] = s0 + b; p1[e] = s1 + b;
    }
    float m0 = p0[0], m1 = p1[0];
#pragma unroll
    for (int e = 1; e < NE; ++e) { m0 = fmaxf(m0, p0[e]); m1 = fmaxf(m1, p1[e]); }
    float sum0 = 0.f, sum1 = 0.f;
#pragma unroll
    for (int e = 0; e < NE; ++e) {
      p0[e] = __expf(p0[e] - m0); sum0 += p0[e];
      p1[e] = __expf(p1[e] - m1); sum1 += p1[e];
    }
    float inv0 = 1.f / sum0, inv1 = 1.f / sum1;
#pragma unroll
    for (int e = 0; e < NE; ++e) { p0[e] *= inv0; p1[e] *= inv1; }
    if (lane == 0) {
#pragma unroll
      for (int j = 0; j < 4; ++j)
        reinterpret_cast<float4*>(probs + (size_t)t0 * NE)[j] =
            make_float4(p0[4 * j], p0[4 * j + 1], p0[4 * j + 2], p0[4 * j + 3]);
      float b1 = -1.f, b2 = -1.f; int i1 = 0, i2 = 0;
#pragma unroll
      for (int e = 0; e < NE; ++e) {
        float pe = p0[e];
        if (pe > b1) { b2 = b1; i2 = i1; b1 = pe; i1 = e; }
        else if (pe > b2) { b2 = pe; i2 = e; }
      }
      float ws = b1 + b2;
      reinterpret_cast<int2*>(topi)[t0] = make_int2(i1, i2);
      reinterpret_cast<float2*>(topw)[t0] = make_float2(b1 / ws, b2 / ws);
      atomicAdd(&hist[i1], 1); atomicAdd(&hist[i2], 1);
    }
    if (lane == 1) {
      int t1 = t0 + 1;
#pragma unroll
      for (int j = 0; j < 4; ++j)
        reinterpret_cast<float4*>(probs + (size_t)t1 * NE)[j] =
            make_float4(p1[4 * j], p1[4 * j + 1], p1[4 * j + 2], p1[4 * j + 3]);
      float b1 = -1.f, b2 = -1.f; int i1 = 0, i2 = 0;
#pragma unroll
      for (int e = 0; e < NE; ++e) {
        float pe = p1[e];
        if (pe > b1) { b2 = b1; i2 = i1; b1 = pe; i1 = e; }
        else if (pe > b2) { b2 = pe; i2 = e; }
      }
      float ws = b1 + b2;
      reinterpret_cast<int2*>(topi)[t1] = make_int2(i1, i2);
      reinterpret_cast<float2*>(topw)[t1] = make_float2(b1 / ws, b2 / ws);
      atomicAdd(&hist[i1], 1); atomicAdd(&hist[i2], 1);
    }
  }
  __syncthreads();
  if (tid < 16) cnt_seg[blockIdx.x * 16 + tid] = hist[tid];
}

// ---------------- scan: parallel prefix over segments, tile table ----------------
__global__ __launch_bounds__(256) void scan_kernel(
    const int* __restrict__ cnt_seg, int* __restrict__ cnt, int* __restrict__ offs,
    int* __restrict__ seg_base, int2* __restrict__ tab) {
  __shared__ int chunk_sum[16][16];   // [chunk][e], chunk = 32 segs
  __shared__ int chunk_base[16][16];
  __shared__ int tot[16], off_s[17];
  int tid = threadIdx.x;
  int e = tid & 15, c = tid >> 4;
  int s0 = 0;
  for (int s = 0; s < 32; ++s) s0 += cnt_seg[(c * 32 + s) * 16 + e];
  chunk_sum[c][e] = s0;
  __syncthreads();
  if (tid < 16) {
    int r = 0;
    for (int c2 = 0; c2 < 16; ++c2) { chunk_base[c2][tid] = r; r += chunk_sum[c2][tid]; }
    tot[tid] = r;
  }
  __syncthreads();
  if (tid == 0) {
    int a = 0;
    for (int i = 0; i < 16; ++i) { off_s[i] = a; offs[i] = a; cnt[i] = tot[i]; a += tot[i]; }
    off_s[16] = RBASE_SHARED; offs[16] = RBASE_SHARED;
    int n = 0;
    for (int g = 0; g <= 16 && n < MAXTILES; ++g) {
      int M = (g == 16) ? T_TOK : tot[g];
      for (int m0 = 0; m0 < M && n < MAXTILES; m0 += 128) { tab[n] = make_int2(g, m0); ++n; }
    }
    for (; n < MAXTILES; ++n) tab[n] = make_int2(-1, 0);
  }
  __syncthreads();
  int r = off_s[e] + chunk_base[c][e];
  for (int s = 0; s < 32; ++s) {
    int seg = c * 32 + s;
    seg_base[seg * 16 + e] = r;
    r += cnt_seg[seg * 16 + e];
  }
}

// ---------------- scatter: deterministic ranks, NO atomics ----------------
// rank of entry (l,s) = #entries (t2,s2) with same expert and (t2,s2) < (l,s)
// lexicographically: s2==0 entries count when t2<l OR (t2==l && s==1);
// s2==1 entries count when t2<l.  (Round-4/5 bug: these two were swapped,
// making every s==1 entry count itself -> slot collisions + poison holes.)
__global__ __launch_bounds__(64) void scatter_kernel(
    const int* __restrict__ topi, const float* __restrict__ topw,
    const int* __restrict__ seg_base,
    int* __restrict__ idx, float* __restrict__ cwl, int* __restrict__ slotmap) {
  __shared__ int ti[16][2]; __shared__ float tw[16][2]; __shared__ int base[16];
  int b = blockIdx.x;            // 512 segments
  int tid = threadIdx.x;         // 64
  if (tid < 16) {
    int t = b * 16 + tid;
    int2 pp = reinterpret_cast<const int2*>(topi)[t];
    ti[tid][0] = clampi(pp.x, 0, 15); ti[tid][1] = clampi(pp.y, 0, 15);
    float2 ww = reinterpret_cast<const float2*>(topw)[t];
    tw[tid][0] = ww.x; tw[tid][1] = ww.y;
    base[tid] = seg_base[b * 16 + tid];
  }
  __syncthreads();
  if (tid < 32) {
    int l = tid >> 1, s = tid & 1;
    int t = b * 16 + l;
    int e = ti[l][s];
    int rank = 0;
    for (int t2 = 0; t2 < 16; ++t2) {
      if (ti[t2][0] == e && (t2 < l || (t2 == l && 0 < s))) ++rank;
      if (ti[t2][1] == e && (t2 < l)) ++rank;
    }
    int slot = clampi(base[e] + rank, 0, NROWS - 1);
    idx[slot] = t; cwl[slot] = tw[l][s]; slotmap[t * 3 + s] = slot;
  } else if (tid < 48) {
    int l = tid - 32;
    int t = b * 16 + l;
    int sh = RBASE_SHARED + t;
    idx[sh] = t; cwl[sh] = 1.0f; slotmap[t * 3 + 2] = sh;
  }
}

// ---------------- grouped GEMM1: G = silu(A@W1^T) * (A@W3^T), bf16 ----------------
__global__ __launch_bounds__(256) void gemm_silu_kernel(
    const u16* __restrict__ A, const u16* __restrict__ sw1b, const u16* __restrict__ sw3b,
    const u16* __restrict__ ew1b, const u16* __restrict__ ew3b, u16* __restrict__ G,
    const int2* __restrict__ tab, const int* __restrict__ offs,
    const int* __restrict__ cnt, const int* __restrict__ gidx) {
  const int K = DIM;
  int2 te = tab[blockIdx.x];
  int e = te.x;
  if (e < 0) return;
  e = clampi(e, 0, NE);
  int m0 = te.y;
  int M = (e == NE) ? T_TOK : cnt[e];
  M = clampi(M, 1, T_TOK);
  int rowbase = clampi(offs[e], 0, NROWS - 1);
  const u16* B1 = (e == NE) ? sw1b : ew1b + (size_t)e * FF * K;
  const u16* B3 = (e == NE) ? sw3b : ew3b + (size_t)e * FF * K;
  int n0 = blockIdx.y * 128;

  __shared__ u16 As[128 * 32], B1s[128 * 32], B3s[128 * 32];

  int tid = threadIdx.x;
  int lane = tid & 63, wv = tid >> 6;
  int srow = tid >> 2, sg = tid & 3;
  int sk0 = (sg ^ ((srow >> 1) & 3)) * 8;
  int sk1 = (sg ^ (((srow + 64) >> 1) & 3)) * 8;
  int r0 = min(m0 + srow, M - 1);
  int r1 = min(m0 + srow + 64, M - 1);
  int ga0 = clampi(gidx[clampi(rowbase + r0, 0, NROWS - 1)], 0, T_TOK - 1);
  int ga1 = clampi(gidx[clampi(rowbase + r1, 0, NROWS - 1)], 0, T_TOK - 1);
  const u16* Ap0 = A + (size_t)ga0 * K + sk0;
  const u16* Ap1 = A + (size_t)ga1 * K + sk1;
  const u16* B1p0 = B1 + (size_t)(n0 + srow) * K + sk0;
  const u16* B1p1 = B1 + (size_t)(n0 + srow + 64) * K + sk1;
  const u16* B3p0 = B3 + (size_t)(n0 + srow) * K + sk0;
  const u16* B3p1 = B3 + (size_t)(n0 + srow + 64) * K + sk1;
  u16* lA0 = As + wv * 512;   u16* lA1 = As + 2048 + wv * 512;
  u16* lB10 = B1s + wv * 512; u16* lB11 = B1s + 2048 + wv * 512;
  u16* lB30 = B3s + wv * 512; u16* lB31 = B3s + 2048 + wv * 512;

  int ln15 = lane & 15, qd = lane >> 4;
  int qsw = (qd ^ ((ln15 >> 1) & 3)) * 8;
  int wm = (wv >> 1) * 64, wn = (wv & 1) * 64;
  int aoff = (wm + ln15) * 32 + qsw;
  int boff = (wn + ln15) * 32 + qsw;

  f32x4 acc1[4][4] = {};
  f32x4 acc3[4][4] = {};

  for (int kt = 0; kt < K; kt += 32) {
    GLL16(Ap0 + kt, lA0);   GLL16(Ap1 + kt, lA1);
    GLL16(B1p0 + kt, lB10); GLL16(B1p1 + kt, lB11);
    GLL16(B3p0 + kt, lB30); GLL16(B3p1 + kt, lB31);
    __syncthreads();
    bf16x8 af[4], b1f[4], b3f[4];
#pragma unroll
    for (int i = 0; i < 4; ++i) {
      af[i]  = *reinterpret_cast<const bf16x8*>(&As[aoff + i * 512]);
      b1f[i] = *reinterpret_cast<const bf16x8*>(&B1s[boff + i * 512]);
      b3f[i] = *reinterpret_cast<const bf16x8*>(&B3s[boff + i * 512]);
    }
#pragma unroll
    for (int i = 0; i < 4; ++i)
#pragma unroll
      for (int j = 0; j < 4; ++j) {
        acc1[i][j] = __builtin_amdgcn_mfma_f32_16x16x32_bf16(af[i], b1f[j], acc1[i][j], 0, 0, 0);
        acc3[i][j] = __builtin_amdgcn_mfma_f32_16x16x32_bf16(af[i], b3f[j], acc3[i][j], 0, 0, 0);
      }
    __syncthreads();
  }

  int mrem = M - m0;
#pragma unroll
  for (int i = 0; i < 4; ++i)
#pragma unroll
    for (int r = 0; r < 4; ++r) {
      int ml = wm + i * 16 + qd * 4 + r;
      if (ml < mrem) {
        size_t orow = (size_t)clampi(rowbase + m0 + ml, 0, NROWS - 1);
#pragma unroll
        for (int j = 0; j < 4; ++j) {
          float z1 = acc1[i][j][r], z3 = acc3[i][j][r];
          float g = z1 / (1.f + __expf(-z1)) * z3;
          G[orow * FF + n0 + wn + j * 16 + ln15] = f2bf(g);
        }
      }
    }
}

// ---------------- grouped GEMM2: O[slot] = cw * (G @ W2^T), bf16 ----------------
__global__ __launch_bounds__(256) void gemm_out_kernel(
    const u16* __restrict__ Gb, const u16* __restrict__ sw2b, const u16* __restrict__ ew2b,
    u16* __restrict__ O, const int2* __restrict__ tab, const int* __restrict__ offs,
    const int* __restrict__ cnt, const float* __restrict__ cwl) {
  const int K = FF;
  int2 te = tab[blockIdx.x];
  int e = te.x;
  if (e < 0) return;
  e = clampi(e, 0, NE);
  int m0 = te.y;
  int M = (e == NE) ? T_TOK : cnt[e];
  M = clampi(M, 1, T_TOK);
  int rowbase = clampi(offs[e], 0, NROWS - 1);
  const u16* B = (e == NE) ? sw2b : ew2b + (size_t)e * DIM * K;
  int n0 = blockIdx.y * 128;

  __shared__ u16 As[128 * 32], Bs[128 * 32];

  int tid = threadIdx.x;
  int lane = tid & 63, wv = tid >> 6;
  int srow = tid >> 2, sg = tid & 3;
  int sk0 = (sg ^ ((srow >> 1) & 3)) * 8;
  int sk1 = (sg ^ (((srow + 64) >> 1) & 3)) * 8;
  int r0 = clampi(rowbase + min(m0 + srow, M - 1), 0, NROWS - 1);
  int r1 = clampi(rowbase + min(m0 + srow + 64, M - 1), 0, NROWS - 1);
  const u16* Ap0 = Gb + (size_t)r0 * K + sk0;
  const u16* Ap1 = Gb + (size_t)r1 * K + sk1;
  const u16* Bp0 = B + (size_t)(n0 + srow) * K + sk0;
  const u16* Bp1 = B + (size_t)(n0 + srow + 64) * K + sk1;
  u16* lA0 = As + wv * 512; u16* lA1 = As + 2048 + wv * 512;
  u16* lB0 = Bs + wv * 512; u16* lB1 = Bs + 2048 + wv * 512;

  int ln15 = lane & 15, qd = lane >> 4;
  int qsw = (qd ^ ((ln15 >> 1) & 3)) * 8;
  int wm = (wv >> 1) * 64, wn = (wv & 1) * 64;
  int aoff = (wm + ln15) * 32 + qsw;
  int boff = (wn + ln15) * 32 + qsw;

  f32x4 acc[4][4] = {};

  for (int kt = 0; kt < K; kt += 32) {
    GLL16(Ap0 + kt, lA0); GLL16(Ap1 + kt, lA1);
    GLL16(Bp0 + kt, lB0); GLL16(Bp1 + kt, lB1);
    __syncthreads();
    bf16x8 af[4], bf[4];
#pragma unroll
    for (int i = 0; i < 4; ++i) {
      af[i] = *reinterpret_cast<const bf16x8*>(&As[aoff + i * 512]);
      bf[i] = *reinterpret_cast<const bf16x8*>(&Bs[boff + i * 512]);
    }
#pragma unroll
    for (int i = 0; i < 4; ++i)
#pragma unroll
      for (int j = 0; j < 4; ++j)
        acc[i][j] = __builtin_amdgcn_mfma_f32_16x16x32_bf16(af[i], bf[j], acc[i][j], 0, 0, 0);
    __syncthreads();
  }

  int mrem = M - m0;
#pragma unroll
  for (int i = 0; i < 4; ++i)
#pragma unroll
    for (int r = 0; r < 4; ++r) {
      int ml = wm + i * 16 + qd * 4 + r;
      if (ml < mrem) {
        int slot = clampi(rowbase + m0 + ml, 0, NROWS - 1);
        float cw = cwl[slot];
#pragma unroll
        for (int j = 0; j < 4; ++j)
          O[(size_t)slot * DIM + n0 + wn + j * 16 + ln15] = f2bf(acc[i][j][r] * cw);
      }
    }
}

// ---------------- combine: y[t] = sum of token's 3 slot rows ----------------
__global__ __launch_bounds__(256) void combine_kernel(
    const u16* __restrict__ O, const int* __restrict__ slotmap, float* __restrict__ y) {
  int t = blockIdx.x;
  int c = threadIdx.x;
  int s0 = clampi(slotmap[t * 3], 0, NROWS - 1);
  int s1 = clampi(slotmap[t * 3 + 1], 0, NROWS - 1);
  int s2 = clampi(slotmap[t * 3 + 2], 0, NROWS - 1);
  ushort4 a = reinterpret_cast<const ushort4*>(O + (size_t)s0 * DIM)[c];
  ushort4 b = reinterpret_cast<const ushort4*>(O + (size_t)s1 * DIM)[c];
  ushort4 d = reinterpret_cast<const ushort4*>(O + (size_t)s2 * DIM)[c];
  float4 r;
  r.x = bf2f(a.x) + bf2f(b.x) + bf2f(d.x);
  r.y = bf2f(a.y) + bf2f(b.y) + bf2f(d.y);
  r.z = bf2f(a.z) + bf2f(b.z) + bf2f(d.z);
  r.w = bf2f(a.w) + bf2f(b.w) + bf2f(d.w);
  reinterpret_cast<float4*>(y + (size_t)t * DIM)[c] = r;
}

// ---------------- launcher ----------------
extern "C" void kernel_launch(void* const* d_in, const int* in_sizes, int n_in,
                              void* d_out, int out_size, void* d_ws, size_t ws_size,
                              hipStream_t stream) {
  const float* x     = (const float*)d_in[0];
  const float* gw    = (const float*)d_in[1];
  const float* ebias = (const float*)d_in[2];
  const float* sw1   = (const float*)d_in[3];
  const float* sw2   = (const float*)d_in[4];
  const float* sw3   = (const float*)d_in[5];
  const float* ew1   = (const float*)d_in[6];
  const float* ew2   = (const float*)d_in[7];
  const float* ew3   = (const float*)d_in[8];
  float* y = (float*)d_out;
  float* probs = y + (size_t)T_TOK * DIM;

  char* ws = (char*)d_ws;
  size_t o = 0;
  auto alloc = [&](size_t bytes) -> char* {
    char* p = ws + o;
    o = (o + bytes + 255) & ~(size_t)255;
    return p;
  };
  u16* G    = (u16*)alloc((size_t)NROWS * FF * 2);
  u16* sw1b = (u16*)alloc((size_t)FF * DIM * 2);
  u16* sw2b = (u16*)alloc((size_t)FF * DIM * 2);
  u16* sw3b = (u16*)alloc((size_t)FF * DIM * 2);
  u16* ew2b = (u16*)alloc((size_t)NE * FF * DIM * 2);
  // aliased region: [xb | ew1b | ew3b] (live through silu) == O (live after silu)
  char* aliasBase = alloc((size_t)NROWS * DIM * 2);
  u16* xb   = (u16*)aliasBase;
  u16* ew1b = (u16*)(aliasBase + (size_t)T_TOK * DIM * 2);
  u16* ew3b = (u16*)(aliasBase + (size_t)T_TOK * DIM * 2 + (size_t)NE * FF * DIM * 2);
  u16* O    = (u16*)aliasBase;
  int*   topi    = (int*)alloc(T_TOK * 2 * 4);
  float* topw    = (float*)alloc(T_TOK * 2 * 4);
  int*   idx     = (int*)alloc(NROWS * 4);
  float* cwl     = (float*)alloc(NROWS * 4);
  int*   slotmap = (int*)alloc(T_TOK * 3 * 4);
  int2*  tab     = (int2*)alloc(MAXTILES * 8);
  int*   cnt_seg = (int*)alloc(NSEG * 16 * 4);
  int*   seg_base= (int*)alloc(NSEG * 16 * 4);
  int*   cnt     = (int*)alloc(256);
  int*   offs    = (int*)alloc(256);

  router_kernel<<<NSEG, 256, 0, stream>>>(x, gw, ebias, probs, topi, topw, cnt_seg);
  scan_kernel<<<1, 256, 0, stream>>>(cnt_seg, cnt, offs, seg_base, tab);
  scatter_kernel<<<NSEG, 64, 0, stream>>>(topi, topw, seg_base, idx, cwl, slotmap);
  cvt_all_kernel<<<TOT4 / 256, 256, 0, stream>>>(x, sw1, sw2, sw3, ew1, ew2, ew3,
                                                 xb, sw1b, sw2b, sw3b, ew1b, ew2b, ew3b);

  gemm_silu_kernel<<<dim3(MAXTILES, 4, 1), 256, 0, stream>>>(
      xb, sw1b, sw3b, ew1b, ew3b, G, tab, offs, cnt, idx);
  gemm_out_kernel<<<dim3(MAXTILES, 8, 1), 256, 0, stream>>>(
      G, sw2b, ew2b, O, tab, offs, cnt, cwl);
  combine_kernel<<<T_TOK, 256, 0, stream>>>(O, slotmap, y);
}